// Round 1
// baseline (532.177 us; speedup 1.0000x reference)
//
#include <hip/hip_runtime.h>

#define NROWS 8192
#define FDIM 256
#define CAP 128   // max edges per row (Poisson λ≈33, P(>=128) ~ 1e-30)

typedef _Float16 half8_t __attribute__((ext_vector_type(8)));
typedef _Float16 half4_t __attribute__((ext_vector_type(4)));
typedef float floatx4 __attribute__((ext_vector_type(4)));

struct MlpPtrs {
  const float* w1[3]; const float* b1[3];
  const float* w2[3]; const float* b2[3];
  const float* gamma[3]; const float* beta[3];
};

// ---------------------------------------------------------------------------
// Task 0/1: q,k fp32->fp16. Tasks 2..4: pack w1[m] to MFMA B-frag order.
// Tasks 5..7: pack w2[m]. Packed layout: ((n_tile*ktiles + k_tile)*64 + lane)*8 + j
// holds W[k_tile*32 + (lane>>4)*8 + j][n_tile*16 + (lane&15)].
// ---------------------------------------------------------------------------
__global__ __launch_bounds__(256) void prep_kernel(
    const float* __restrict__ q, const float* __restrict__ k, MlpPtrs p,
    _Float16* __restrict__ qh, _Float16* __restrict__ kh,
    _Float16* __restrict__ w1p, _Float16* __restrict__ w2p) {
  int task = blockIdx.y;
  int tid = blockIdx.x * 256 + threadIdx.x;
  if (task == 0) { if (tid < NROWS * 128) qh[tid] = (_Float16)q[tid]; return; }
  if (task == 1) { if (tid < NROWS * 128) kh[tid] = (_Float16)k[tid]; return; }
  int m = (task - 2) % 3;
  bool isw2 = task >= 5;
  int K = isw2 ? 256 : 128;
  if (tid >= K * 256) return;
  const float* src = isw2 ? p.w2[m] : p.w1[m];
  _Float16* dst = isw2 ? (w2p + m * 65536) : (w1p + m * 32768);
  int j = tid & 7, lane = (tid >> 3) & 63, rest = tid >> 9;
  int ktiles = K >> 5;
  int k_tile = rest % ktiles, n_tile = rest / ktiles;
  int kk = k_tile * 32 + (lane >> 4) * 8 + j;
  int nn = n_tile * 16 + (lane & 15);
  dst[tid] = (_Float16)src[kk * 256 + nn];
}

// ---------------------------------------------------------------------------
// A-scan: one block per row, compact nonzero column indices (A is binary).
// ---------------------------------------------------------------------------
__global__ __launch_bounds__(256) void ascan_kernel(
    const float* __restrict__ A, int* __restrict__ rowcnt, int* __restrict__ colidx) {
  int i = blockIdx.x;
  __shared__ int cnt;
  if (threadIdx.x == 0) cnt = 0;
  __syncthreads();
  const float4* row = (const float4*)(A + (size_t)i * NROWS);
  int* dst = colidx + (size_t)i * CAP;
  #pragma unroll
  for (int it = 0; it < 8; ++it) {
    int v4 = it * 256 + threadIdx.x;
    float4 v = row[v4];
    int cols[4]; int c = 0;
    if (v.x != 0.f) cols[c++] = v4 * 4 + 0;
    if (v.y != 0.f) cols[c++] = v4 * 4 + 1;
    if (v.z != 0.f) cols[c++] = v4 * 4 + 2;
    if (v.w != 0.f) cols[c++] = v4 * 4 + 3;
    if (c) {
      int pos = atomicAdd(&cnt, c);
      for (int l = 0; l < c; ++l) if (pos + l < CAP) dst[pos + l] = cols[l];
    }
  }
  __syncthreads();
  if (threadIdx.x == 0) rowcnt[i] = cnt > CAP ? CAP : cnt;
}

// ---------------------------------------------------------------------------
// GEMM1: h1 = leaky(X @ w1 + b1).  X: [8192,128] fp16, w1 packed, out fp16.
// Block = 4 waves; wave computes 16 rows x 64 cols via 4 MFMA accumulators.
// ---------------------------------------------------------------------------
__global__ __launch_bounds__(256) void gemm1_kernel(
    const _Float16* __restrict__ qh, const _Float16* __restrict__ kh,
    const _Float16* __restrict__ w1p, MlpPtrs p, _Float16* __restrict__ h1) {
  const int mlp = blockIdx.z;
  const _Float16* X = (mlp == 0) ? qh : kh;
  const _Float16* wp = w1p + mlp * 32768;
  _Float16* out = h1 + (size_t)mlp * (NROWS * FDIM);
  const float* bias = p.b1[mlp];
  int lane = threadIdx.x & 63, wave = threadIdx.x >> 6;
  int lm = lane & 15, lq = lane >> 4;
  int m0 = blockIdx.x * 64 + wave * 16;
  int n0 = blockIdx.y * 64;
  floatx4 acc[4];
  #pragma unroll
  for (int t = 0; t < 4; ++t) acc[t] = (floatx4){0.f, 0.f, 0.f, 0.f};
  const half8_t* ap = (const half8_t*)(X + (size_t)(m0 + lm) * 128 + lq * 8);
  const half8_t* wp8 = (const half8_t*)wp;
  #pragma unroll
  for (int kt = 0; kt < 4; ++kt) {
    half8_t a = ap[kt * 4];
    #pragma unroll
    for (int t = 0; t < 4; ++t) {
      half8_t b = wp8[(((n0 >> 4) + t) * 4 + kt) * 64 + lane];
      acc[t] = __builtin_amdgcn_mfma_f32_16x16x32_f16(a, b, acc[t], 0, 0, 0);
    }
  }
  #pragma unroll
  for (int t = 0; t < 4; ++t) {
    int col = n0 + t * 16 + lm;
    float bb = bias[col];
    #pragma unroll
    for (int r = 0; r < 4; ++r) {
      float v = acc[t][r] + bb;
      v = (v >= 0.f) ? v : 0.01f * v;
      out[(size_t)(m0 + lq * 4 + r) * FDIM + col] = (_Float16)v;
    }
  }
}

// ---------------------------------------------------------------------------
// GEMM2: h2 = leaky(h1 @ w2 + b2) (stored fp16, normalized in-place later),
// plus BN column sums / sumsq via shfl-reduce + global atomics.
// ---------------------------------------------------------------------------
__global__ __launch_bounds__(256) void gemm2_kernel(
    const _Float16* __restrict__ h1, const _Float16* __restrict__ w2p,
    MlpPtrs p, _Float16* __restrict__ e1,
    float* __restrict__ colsum, float* __restrict__ colsumsq) {
  const int mlp = blockIdx.z;
  const _Float16* X = h1 + (size_t)mlp * (NROWS * FDIM);
  const _Float16* wp = w2p + mlp * 65536;
  _Float16* out = e1 + (size_t)mlp * (NROWS * FDIM);
  const float* bias = p.b2[mlp];
  int lane = threadIdx.x & 63, wave = threadIdx.x >> 6;
  int lm = lane & 15, lq = lane >> 4;
  int m0 = blockIdx.x * 64 + wave * 16;
  int n0 = blockIdx.y * 64;
  floatx4 acc[4];
  #pragma unroll
  for (int t = 0; t < 4; ++t) acc[t] = (floatx4){0.f, 0.f, 0.f, 0.f};
  const half8_t* ap = (const half8_t*)(X + (size_t)(m0 + lm) * 256 + lq * 8);
  const half8_t* wp8 = (const half8_t*)wp;
  #pragma unroll
  for (int kt = 0; kt < 8; ++kt) {
    half8_t a = ap[kt * 4];
    #pragma unroll
    for (int t = 0; t < 4; ++t) {
      half8_t b = wp8[(((n0 >> 4) + t) * 8 + kt) * 64 + lane];
      acc[t] = __builtin_amdgcn_mfma_f32_16x16x32_f16(a, b, acc[t], 0, 0, 0);
    }
  }
  #pragma unroll
  for (int t = 0; t < 4; ++t) {
    int col = n0 + t * 16 + lm;
    float bb = bias[col];
    float s = 0.f, s2 = 0.f;
    #pragma unroll
    for (int r = 0; r < 4; ++r) {
      float v = acc[t][r] + bb;
      v = (v >= 0.f) ? v : 0.01f * v;
      out[(size_t)(m0 + lq * 4 + r) * FDIM + col] = (_Float16)v;
      s += v; s2 += v * v;
    }
    s  += __shfl_xor(s, 16, 64);  s  += __shfl_xor(s, 32, 64);
    s2 += __shfl_xor(s2, 16, 64); s2 += __shfl_xor(s2, 32, 64);
    if (lq == 0) {
      atomicAdd(&colsum[mlp * FDIM + col], s);
      atomicAdd(&colsumsq[mlp * FDIM + col], s2);
    }
  }
}

// ---------------------------------------------------------------------------
// BN normalize in-place (fp16). Each block: 32 rows, thread = column.
// mlp==2 (v) also accumulates S_all = column sums of ve1 (post-round).
// ---------------------------------------------------------------------------
__global__ __launch_bounds__(256) void norm_kernel(
    _Float16* __restrict__ e1, const float* __restrict__ colsum,
    const float* __restrict__ colsumsq, MlpPtrs p, float* __restrict__ S_all) {
  int mlp = blockIdx.y;
  int c = threadIdx.x;
  _Float16* h = e1 + (size_t)mlp * (NROWS * FDIM);
  float mean = colsum[mlp * FDIM + c] * (1.f / NROWS);
  float var = colsumsq[mlp * FDIM + c] * (1.f / NROWS) - mean * mean;
  float scale = p.gamma[mlp][c] * rsqrtf(var + 1e-5f);
  float shift = p.beta[mlp][c] - mean * scale;
  int r0 = blockIdx.x * 32;
  float sv = 0.f;
  for (int r = 0; r < 32; ++r) {
    size_t idx = (size_t)(r0 + r) * FDIM + c;
    float v = (float)h[idx] * scale + shift;
    _Float16 hv = (_Float16)v;
    h[idx] = hv;
    sv += (float)hv;
  }
  if (mlp == 2) atomicAdd(&S_all[c], sv);
}

// ---------------------------------------------------------------------------
// Fused sparse SDDMM + softmax(with implicit zeros) + SpMM. Block per row.
// Phase A: wave-per-edge dot(qe1_i, ke1_j)/16. Phase B: m, denom.
// Phase C: thread-per-column AXPY over edges + uniform background term.
// ---------------------------------------------------------------------------
__global__ __launch_bounds__(256) void attn_kernel(
    const int* __restrict__ rowcnt, const int* __restrict__ colidx,
    const _Float16* __restrict__ e1, const float* __restrict__ S_all,
    float* __restrict__ out) {
  const _Float16* qe = e1;
  const _Float16* ke = e1 + (size_t)1 * NROWS * FDIM;
  const _Float16* ve = e1 + (size_t)2 * NROWS * FDIM;
  int i = blockIdx.x;
  int tid = threadIdx.x, lane = tid & 63, wave = tid >> 6;
  __shared__ float sw[CAP];
  __shared__ int sj[CAP];
  __shared__ float red[4];
  __shared__ float sm_m, sm_em, sm_inv;
  int nnz = rowcnt[i];

  half4_t qv = *(const half4_t*)(qe + (size_t)i * FDIM + 4 * lane);
  float q0 = qv[0], q1 = qv[1], q2 = qv[2], q3 = qv[3];
  for (int e = wave; e < nnz; e += 4) {
    int j = colidx[(size_t)i * CAP + e];
    half4_t kv = *(const half4_t*)(ke + (size_t)j * FDIM + 4 * lane);
    float s = q0 * (float)kv[0] + q1 * (float)kv[1] + q2 * (float)kv[2] + q3 * (float)kv[3];
    #pragma unroll
    for (int off = 32; off >= 1; off >>= 1) s += __shfl_xor(s, off, 64);
    if (lane == 0) { sw[e] = s * 0.0625f; sj[e] = j; }
  }
  __syncthreads();

  float lm = 0.f;  // zeros always present in the row -> max includes 0
  for (int e = tid; e < nnz; e += 256) lm = fmaxf(lm, sw[e]);
  #pragma unroll
  for (int off = 32; off >= 1; off >>= 1) lm = fmaxf(lm, __shfl_xor(lm, off, 64));
  if (lane == 0) red[wave] = lm;
  __syncthreads();
  if (tid == 0) {
    float m = fmaxf(fmaxf(red[0], red[1]), fmaxf(red[2], red[3]));
    sm_m = m;
    sm_em = expf(-m);
  }
  __syncthreads();
  float m = sm_m, em = sm_em;

  float ls = 0.f;
  for (int e = tid; e < nnz; e += 256) {
    float w = expf(sw[e] - m);
    ls += w;
    sw[e] = w - em;  // edge weight minus background
  }
  #pragma unroll
  for (int off = 32; off >= 1; off >>= 1) ls += __shfl_xor(ls, off, 64);
  if (lane == 0) red[wave] = ls;
  __syncthreads();
  if (tid == 0) {
    float denom = red[0] + red[1] + red[2] + red[3] + (float)(NROWS - nnz) * em;
    sm_inv = 1.f / denom;
  }
  __syncthreads();
  float inv = sm_inv;

  int c = tid;
  float acc = em * S_all[c];
  for (int e = 0; e < nnz; ++e) {
    int j = sj[e];
    float w = sw[e];
    acc += w * (float)ve[(size_t)j * FDIM + c];
  }
  out[(size_t)i * FDIM + c] = acc * inv;
}

// ---------------------------------------------------------------------------
extern "C" void kernel_launch(void* const* d_in, const int* in_sizes, int n_in,
                              void* d_out, int out_size, void* d_ws, size_t ws_size,
                              hipStream_t stream) {
  const float* A = (const float*)d_in[0];
  const float* q = (const float*)d_in[1];
  const float* k = (const float*)d_in[2];
  MlpPtrs p;
  for (int m = 0; m < 3; ++m) {
    const int b = 3 + m * 6;
    p.w1[m]    = (const float*)d_in[b + 0];
    p.b1[m]    = (const float*)d_in[b + 1];
    p.w2[m]    = (const float*)d_in[b + 2];
    p.b2[m]    = (const float*)d_in[b + 3];
    p.gamma[m] = (const float*)d_in[b + 4];
    p.beta[m]  = (const float*)d_in[b + 5];
  }
  char* ws = (char*)d_ws;
  const size_t MB = 1024 * 1024;
  _Float16* qh  = (_Float16*)(ws + 0);                 // 2 MB
  _Float16* kh  = (_Float16*)(ws + 2 * MB);            // 2 MB
  _Float16* h1  = (_Float16*)(ws + 4 * MB);            // 12 MB (3 x 4MB)
  _Float16* e1  = (_Float16*)(ws + 16 * MB);           // 12 MB (3 x 4MB), h2 then normalized in-place
  _Float16* w1p = (_Float16*)(ws + 28 * MB);           // 192 KB
  _Float16* w2p = (_Float16*)(ws + 28 * MB + 192 * 1024); // 384 KB
  float* colsum   = (float*)(ws + 28 * MB + 640 * 1024);  // 3*256 f
  float* colsumsq = colsum + 3 * FDIM;                    // 3*256 f
  float* S_all    = colsumsq + 3 * FDIM;                  // 256 f
  int* rowcnt = (int*)(ws + 28 * MB + 648 * 1024);        // 32 KB
  int* colidx = (int*)(ws + 30 * MB);                     // 4 MB

  hipMemsetAsync(colsum, 0, 7 * 1024, stream);
  prep_kernel<<<dim3(4096, 8, 1), 256, 0, stream>>>(q, k, p, qh, kh, w1p, w2p);
  ascan_kernel<<<NROWS, 256, 0, stream>>>(A, rowcnt, colidx);
  gemm1_kernel<<<dim3(128, 4, 3), 256, 0, stream>>>(qh, kh, w1p, p, h1);
  gemm2_kernel<<<dim3(128, 4, 3), 256, 0, stream>>>(h1, w2p, p, e1, colsum, colsumsq);
  norm_kernel<<<dim3(256, 3, 1), 256, 0, stream>>>(e1, colsum, colsumsq, p, S_all);
  attn_kernel<<<NROWS, 256, 0, stream>>>(rowcnt, colidx, e1, S_all, (float*)d_out);
}

// Round 3
// 488.036 us; speedup vs baseline: 1.0904x; 1.0904x over previous
//
#include <hip/hip_runtime.h>

#define NROWS 8192
#define FDIM 256
#define CAP 128   // max edges per row (Poisson lambda~33, P(>=128) ~ 1e-30)

typedef _Float16 half8_t __attribute__((ext_vector_type(8)));
typedef _Float16 half4_t __attribute__((ext_vector_type(4)));
typedef float floatx4 __attribute__((ext_vector_type(4)));

struct MlpPtrs {
  const float* w1[3]; const float* b1[3];
  const float* w2[3]; const float* b2[3];
  const float* gamma[3]; const float* beta[3];
};

// ---------------------------------------------------------------------------
// Task 0/1: q,k fp32->fp16. Tasks 2..4: pack w1[m] to MFMA B-frag order.
// Tasks 5..7: pack w2[m]. Packed layout: ((n_tile*ktiles + k_tile)*64 + lane)*8 + j
// holds W[k_tile*32 + (lane>>4)*8 + j][n_tile*16 + (lane&15)].
// ---------------------------------------------------------------------------
__global__ __launch_bounds__(256) void prep_kernel(
    const float* __restrict__ q, const float* __restrict__ k, MlpPtrs p,
    _Float16* __restrict__ qh, _Float16* __restrict__ kh,
    _Float16* __restrict__ w1p, _Float16* __restrict__ w2p) {
  int task = blockIdx.y;
  int tid = blockIdx.x * 256 + threadIdx.x;
  if (task == 0) { if (tid < NROWS * 128) qh[tid] = (_Float16)q[tid]; return; }
  if (task == 1) { if (tid < NROWS * 128) kh[tid] = (_Float16)k[tid]; return; }
  int m = (task - 2) % 3;
  bool isw2 = task >= 5;
  int K = isw2 ? 256 : 128;
  if (tid >= K * 256) return;
  const float* src = isw2 ? p.w2[m] : p.w1[m];
  _Float16* dst = isw2 ? (w2p + m * 65536) : (w1p + m * 32768);
  int j = tid & 7, lane = (tid >> 3) & 63, rest = tid >> 9;
  int ktiles = K >> 5;
  int k_tile = rest % ktiles, n_tile = rest / ktiles;
  int kk = k_tile * 32 + (lane >> 4) * 8 + j;
  int nn = n_tile * 16 + (lane & 15);
  dst[tid] = (_Float16)src[kk * 256 + nn];
}

// ---------------------------------------------------------------------------
// GEMM1: h1 = leaky(X @ w1 + b1).  X: [8192,128] fp16, w1 packed, out fp16.
// ---------------------------------------------------------------------------
__global__ __launch_bounds__(256) void gemm1_kernel(
    const _Float16* __restrict__ qh, const _Float16* __restrict__ kh,
    const _Float16* __restrict__ w1p, MlpPtrs p, _Float16* __restrict__ h1) {
  const int mlp = blockIdx.z;
  const _Float16* X = (mlp == 0) ? qh : kh;
  const _Float16* wp = w1p + mlp * 32768;
  _Float16* out = h1 + (size_t)mlp * (NROWS * FDIM);
  const float* bias = p.b1[mlp];
  int lane = threadIdx.x & 63, wave = threadIdx.x >> 6;
  int lm = lane & 15, lq = lane >> 4;
  int m0 = blockIdx.x * 64 + wave * 16;
  int n0 = blockIdx.y * 64;
  floatx4 acc[4];
  #pragma unroll
  for (int t = 0; t < 4; ++t) acc[t] = (floatx4){0.f, 0.f, 0.f, 0.f};
  const half8_t* ap = (const half8_t*)(X + (size_t)(m0 + lm) * 128 + lq * 8);
  const half8_t* wp8 = (const half8_t*)wp;
  #pragma unroll
  for (int kt = 0; kt < 4; ++kt) {
    half8_t a = ap[kt * 4];
    #pragma unroll
    for (int t = 0; t < 4; ++t) {
      half8_t b = wp8[(((n0 >> 4) + t) * 4 + kt) * 64 + lane];
      acc[t] = __builtin_amdgcn_mfma_f32_16x16x32_f16(a, b, acc[t], 0, 0, 0);
    }
  }
  #pragma unroll
  for (int t = 0; t < 4; ++t) {
    int col = n0 + t * 16 + lm;
    float bb = bias[col];
    #pragma unroll
    for (int r = 0; r < 4; ++r) {
      float v = acc[t][r] + bb;
      v = (v >= 0.f) ? v : 0.01f * v;
      out[(size_t)(m0 + lq * 4 + r) * FDIM + col] = (_Float16)v;
    }
  }
}

// ---------------------------------------------------------------------------
// GEMM2: h2 = leaky(h1 @ w2 + b2) + BN column sums via shfl + atomics.
// ---------------------------------------------------------------------------
__global__ __launch_bounds__(256) void gemm2_kernel(
    const _Float16* __restrict__ h1, const _Float16* __restrict__ w2p,
    MlpPtrs p, _Float16* __restrict__ e1,
    float* __restrict__ colsum, float* __restrict__ colsumsq) {
  const int mlp = blockIdx.z;
  const _Float16* X = h1 + (size_t)mlp * (NROWS * FDIM);
  const _Float16* wp = w2p + mlp * 65536;
  _Float16* out = e1 + (size_t)mlp * (NROWS * FDIM);
  const float* bias = p.b2[mlp];
  int lane = threadIdx.x & 63, wave = threadIdx.x >> 6;
  int lm = lane & 15, lq = lane >> 4;
  int m0 = blockIdx.x * 64 + wave * 16;
  int n0 = blockIdx.y * 64;
  floatx4 acc[4];
  #pragma unroll
  for (int t = 0; t < 4; ++t) acc[t] = (floatx4){0.f, 0.f, 0.f, 0.f};
  const half8_t* ap = (const half8_t*)(X + (size_t)(m0 + lm) * 256 + lq * 8);
  const half8_t* wp8 = (const half8_t*)wp;
  #pragma unroll
  for (int kt = 0; kt < 8; ++kt) {
    half8_t a = ap[kt * 4];
    #pragma unroll
    for (int t = 0; t < 4; ++t) {
      half8_t b = wp8[(((n0 >> 4) + t) * 8 + kt) * 64 + lane];
      acc[t] = __builtin_amdgcn_mfma_f32_16x16x32_f16(a, b, acc[t], 0, 0, 0);
    }
  }
  #pragma unroll
  for (int t = 0; t < 4; ++t) {
    int col = n0 + t * 16 + lm;
    float bb = bias[col];
    float s = 0.f, s2 = 0.f;
    #pragma unroll
    for (int r = 0; r < 4; ++r) {
      float v = acc[t][r] + bb;
      v = (v >= 0.f) ? v : 0.01f * v;
      out[(size_t)(m0 + lq * 4 + r) * FDIM + col] = (_Float16)v;
      s += v; s2 += v * v;
    }
    s  += __shfl_xor(s, 16, 64);  s  += __shfl_xor(s, 32, 64);
    s2 += __shfl_xor(s2, 16, 64); s2 += __shfl_xor(s2, 32, 64);
    if (lq == 0) {
      atomicAdd(&colsum[mlp * FDIM + col], s);
      atomicAdd(&colsumsq[mlp * FDIM + col], s2);
    }
  }
}

// ---------------------------------------------------------------------------
// BN normalize in-place (fp16); mlp==2 also accumulates S_all (post-round).
// ---------------------------------------------------------------------------
__global__ __launch_bounds__(256) void norm_kernel(
    _Float16* __restrict__ e1, const float* __restrict__ colsum,
    const float* __restrict__ colsumsq, MlpPtrs p, float* __restrict__ S_all) {
  int mlp = blockIdx.y;
  int c = threadIdx.x;
  _Float16* h = e1 + (size_t)mlp * (NROWS * FDIM);
  float mean = colsum[mlp * FDIM + c] * (1.f / NROWS);
  float var = colsumsq[mlp * FDIM + c] * (1.f / NROWS) - mean * mean;
  float scale = p.gamma[mlp][c] * rsqrtf(var + 1e-5f);
  float shift = p.beta[mlp][c] - mean * scale;
  int r0 = blockIdx.x * 32;
  float sv = 0.f;
  for (int r = 0; r < 32; ++r) {
    size_t idx = (size_t)(r0 + r) * FDIM + c;
    float v = (float)h[idx] * scale + shift;
    _Float16 hv = (_Float16)v;
    h[idx] = hv;
    sv += (float)hv;
  }
  if (mlp == 2) atomicAdd(&S_all[c], sv);
}

// ---------------------------------------------------------------------------
// Fused: A-row scan (nontemporal stream) + sparse SDDMM + softmax-with-
// implicit-zeros + SpMM.  One block per row, 4 waves.
// ---------------------------------------------------------------------------
__global__ __launch_bounds__(256) void attn_kernel(
    const float* __restrict__ A,
    const _Float16* __restrict__ e1, const float* __restrict__ S_all,
    float* __restrict__ out) {
  const _Float16* qe = e1;
  const _Float16* ke = e1 + (size_t)1 * NROWS * FDIM;
  const _Float16* ve = e1 + (size_t)2 * NROWS * FDIM;
  int i = blockIdx.x;
  int tid = threadIdx.x, lane = tid & 63, wave = tid >> 6;
  __shared__ int sj[CAP];
  __shared__ float sw[CAP];
  __shared__ float pacc[4][FDIM];
  __shared__ int s_cnt;
  __shared__ float sm_em, sm_inv;
  if (tid == 0) s_cnt = 0;
  __syncthreads();

  // -------- scan A row i (streamed, nontemporal: don't evict e1 from L2/L3)
  const floatx4* row = (const floatx4*)(A + (size_t)i * NROWS);
  #pragma unroll
  for (int it = 0; it < 8; ++it) {
    int v4 = it * 256 + tid;
    floatx4 v = __builtin_nontemporal_load(&row[v4]);
    int cols[4]; int c = 0;
    if (v[0] != 0.f) cols[c++] = v4 * 4 + 0;
    if (v[1] != 0.f) cols[c++] = v4 * 4 + 1;
    if (v[2] != 0.f) cols[c++] = v4 * 4 + 2;
    if (v[3] != 0.f) cols[c++] = v4 * 4 + 3;
    if (c) {
      int pos = atomicAdd(&s_cnt, c);
      for (int l = 0; l < c; ++l) if (pos + l < CAP) sj[pos + l] = cols[l];
    }
  }
  __syncthreads();
  int nnz = s_cnt < CAP ? s_cnt : CAP;

  // -------- SDDMM: scores for each edge
  half4_t qv = *(const half4_t*)(qe + (size_t)i * FDIM + 4 * lane);
  float q0 = qv[0], q1 = qv[1], q2 = qv[2], q3 = qv[3];
  for (int e = wave; e < nnz; e += 4) {
    int j = sj[e];
    half4_t kv = *(const half4_t*)(ke + (size_t)j * FDIM + 4 * lane);
    float s = q0 * (float)kv[0] + q1 * (float)kv[1] + q2 * (float)kv[2] + q3 * (float)kv[3];
    #pragma unroll
    for (int off = 32; off >= 1; off >>= 1) s += __shfl_xor(s, off, 64);
    if (lane == 0) sw[e] = s * 0.0625f;
  }
  __syncthreads();

  // -------- softmax reduction: wave 0 only (nnz <= 128 = 2 elems/lane)
  if (wave == 0) {
    bool v0ok = lane < nnz, v1ok = lane + 64 < nnz;
    float v0 = v0ok ? sw[lane] : 0.f;
    float v1 = v1ok ? sw[lane + 64] : 0.f;
    float lm = fmaxf(fmaxf(v0, v1), 0.f);  // background zeros participate
    #pragma unroll
    for (int off = 32; off >= 1; off >>= 1) lm = fmaxf(lm, __shfl_xor(lm, off, 64));
    float m = lm;
    float em = expf(-m);
    float w0 = v0ok ? expf(v0 - m) : 0.f;
    float w1 = v1ok ? expf(v1 - m) : 0.f;
    float ls = w0 + w1;
    #pragma unroll
    for (int off = 32; off >= 1; off >>= 1) ls += __shfl_xor(ls, off, 64);
    if (v0ok) sw[lane] = w0 - em;        // edge weight minus background
    if (v1ok) sw[lane + 64] = w1 - em;
    if (lane == 0) {
      sm_em = em;
      sm_inv = 1.f / (ls + (float)(NROWS - nnz) * em);
    }
  }
  __syncthreads();

  // -------- SpMM: wave-split edges, lane covers 4 columns
  float a0 = 0.f, a1 = 0.f, a2 = 0.f, a3 = 0.f;
  for (int e = wave; e < nnz; e += 4) {
    int j = sj[e];
    float w = sw[e];
    half4_t vv = *(const half4_t*)(ve + (size_t)j * FDIM + 4 * lane);
    a0 += w * (float)vv[0];
    a1 += w * (float)vv[1];
    a2 += w * (float)vv[2];
    a3 += w * (float)vv[3];
  }
  ((floatx4*)pacc[wave])[lane] = (floatx4){a0, a1, a2, a3};
  __syncthreads();

  int c = tid;
  float em = sm_em, inv = sm_inv;
  float s = pacc[0][c] + pacc[1][c] + pacc[2][c] + pacc[3][c] + em * S_all[c];
  __builtin_nontemporal_store(s * inv, &out[(size_t)i * FDIM + c]);
}

// ---------------------------------------------------------------------------
extern "C" void kernel_launch(void* const* d_in, const int* in_sizes, int n_in,
                              void* d_out, int out_size, void* d_ws, size_t ws_size,
                              hipStream_t stream) {
  const float* A = (const float*)d_in[0];
  const float* q = (const float*)d_in[1];
  const float* k = (const float*)d_in[2];
  MlpPtrs p;
  for (int m = 0; m < 3; ++m) {
    const int b = 3 + m * 6;
    p.w1[m]    = (const float*)d_in[b + 0];
    p.b1[m]    = (const float*)d_in[b + 1];
    p.w2[m]    = (const float*)d_in[b + 2];
    p.b2[m]    = (const float*)d_in[b + 3];
    p.gamma[m] = (const float*)d_in[b + 4];
    p.beta[m]  = (const float*)d_in[b + 5];
  }
  char* ws = (char*)d_ws;
  const size_t MB = 1024 * 1024;
  _Float16* qh  = (_Float16*)(ws + 0);                 // 2 MB
  _Float16* kh  = (_Float16*)(ws + 2 * MB);            // 2 MB
  _Float16* h1  = (_Float16*)(ws + 4 * MB);            // 12 MB (3 x 4MB)
  _Float16* e1  = (_Float16*)(ws + 16 * MB);           // 12 MB (3 x 4MB)
  _Float16* w1p = (_Float16*)(ws + 28 * MB);           // 192 KB
  _Float16* w2p = (_Float16*)(ws + 28 * MB + 192 * 1024); // 384 KB
  float* colsum   = (float*)(ws + 28 * MB + 640 * 1024);  // 3*256 f
  float* colsumsq = colsum + 3 * FDIM;                    // 3*256 f
  float* S_all    = colsumsq + 3 * FDIM;                  // 256 f

  (void)hipMemsetAsync(colsum, 0, 7 * 1024, stream);
  prep_kernel<<<dim3(4096, 8, 1), 256, 0, stream>>>(q, k, p, qh, kh, w1p, w2p);
  gemm1_kernel<<<dim3(128, 4, 3), 256, 0, stream>>>(qh, kh, w1p, p, h1);
  gemm2_kernel<<<dim3(128, 4, 3), 256, 0, stream>>>(h1, w2p, p, e1, colsum, colsumsq);
  norm_kernel<<<dim3(256, 3, 1), 256, 0, stream>>>(e1, colsum, colsumsq, p, S_all);
  attn_kernel<<<NROWS, 256, 0, stream>>>(A, e1, S_all, (float*)d_out);
}

// Round 4
// 457.984 us; speedup vs baseline: 1.1620x; 1.0656x over previous
//
#include <hip/hip_runtime.h>

#define NROWS 8192
#define FDIM 256
#define CAP 128   // max edges per row (Poisson lambda~33, P(>=128) ~ 1e-30)

typedef _Float16 half8_t __attribute__((ext_vector_type(8)));
typedef _Float16 half4_t __attribute__((ext_vector_type(4)));
typedef float floatx4 __attribute__((ext_vector_type(4)));

struct MlpPtrs {
  const float* w1[3]; const float* b1[3];
  const float* w2[3]; const float* b2[3];
  const float* gamma[3]; const float* beta[3];
};

// ---------------------------------------------------------------------------
// Task 0/1: q,k fp32->fp16 (grid-stride float4->half4). Tasks 2..4: pack w1[m]
// to MFMA B-frag order. Tasks 5..7: pack w2[m].
// Packed layout: ((n_tile*ktiles + k_tile)*64 + lane)*8 + j holds
// W[k_tile*32 + (lane>>4)*8 + j][n_tile*16 + (lane&15)].
// ---------------------------------------------------------------------------
__global__ __launch_bounds__(256) void prep_kernel(
    const float* __restrict__ q, const float* __restrict__ k, MlpPtrs p,
    _Float16* __restrict__ qh, _Float16* __restrict__ kh,
    _Float16* __restrict__ w1p, _Float16* __restrict__ w2p) {
  int task = blockIdx.y;
  int tid = blockIdx.x * 256 + threadIdx.x;
  if (task < 2) {
    const float* src = task == 0 ? q : k;
    _Float16* dst = task == 0 ? qh : kh;
    const floatx4* s4 = (const floatx4*)src;
    half4_t* d4 = (half4_t*)dst;
    for (int idx = tid; idx < (NROWS * 128) / 4; idx += 256 * 256) {
      floatx4 v = s4[idx];
      d4[idx] = (half4_t){(_Float16)v[0], (_Float16)v[1], (_Float16)v[2], (_Float16)v[3]};
    }
    return;
  }
  int m = (task - 2) % 3;
  bool isw2 = task >= 5;
  int K = isw2 ? 256 : 128;
  if (tid >= K * 256) return;
  const float* src = isw2 ? p.w2[m] : p.w1[m];
  _Float16* dst = isw2 ? (w2p + m * 65536) : (w1p + m * 32768);
  int j = tid & 7, lane = (tid >> 3) & 63, rest = tid >> 9;
  int ktiles = K >> 5;
  int k_tile = rest % ktiles, n_tile = rest / ktiles;
  int kk = k_tile * 32 + (lane >> 4) * 8 + j;
  int nn = n_tile * 16 + (lane & 15);
  dst[tid] = (_Float16)src[kk * 256 + nn];
}

// ---------------------------------------------------------------------------
// GEMM1: h1 = leaky(X @ w1 + b1).  X: [8192,128] fp16, w1 packed, out fp16.
// ---------------------------------------------------------------------------
__global__ __launch_bounds__(256) void gemm1_kernel(
    const _Float16* __restrict__ qh, const _Float16* __restrict__ kh,
    const _Float16* __restrict__ w1p, MlpPtrs p, _Float16* __restrict__ h1) {
  const int mlp = blockIdx.z;
  const _Float16* X = (mlp == 0) ? qh : kh;
  const _Float16* wp = w1p + mlp * 32768;
  _Float16* out = h1 + (size_t)mlp * (NROWS * FDIM);
  const float* bias = p.b1[mlp];
  int lane = threadIdx.x & 63, wave = threadIdx.x >> 6;
  int lm = lane & 15, lq = lane >> 4;
  int m0 = blockIdx.x * 64 + wave * 16;
  int n0 = blockIdx.y * 64;
  floatx4 acc[4];
  #pragma unroll
  for (int t = 0; t < 4; ++t) acc[t] = (floatx4){0.f, 0.f, 0.f, 0.f};
  const half8_t* ap = (const half8_t*)(X + (size_t)(m0 + lm) * 128 + lq * 8);
  const half8_t* wp8 = (const half8_t*)wp;
  #pragma unroll
  for (int kt = 0; kt < 4; ++kt) {
    half8_t a = ap[kt * 4];
    #pragma unroll
    for (int t = 0; t < 4; ++t) {
      half8_t b = wp8[(((n0 >> 4) + t) * 4 + kt) * 64 + lane];
      acc[t] = __builtin_amdgcn_mfma_f32_16x16x32_f16(a, b, acc[t], 0, 0, 0);
    }
  }
  #pragma unroll
  for (int t = 0; t < 4; ++t) {
    int col = n0 + t * 16 + lm;
    float bb = bias[col];
    #pragma unroll
    for (int r = 0; r < 4; ++r) {
      float v = acc[t][r] + bb;
      v = (v >= 0.f) ? v : 0.01f * v;
      out[(size_t)(m0 + lq * 4 + r) * FDIM + col] = (_Float16)v;
    }
  }
}

// ---------------------------------------------------------------------------
// GEMM2: h2 = leaky(h1 @ w2 + b2) + BN column sums via shfl + atomics.
// ---------------------------------------------------------------------------
__global__ __launch_bounds__(256) void gemm2_kernel(
    const _Float16* __restrict__ h1, const _Float16* __restrict__ w2p,
    MlpPtrs p, _Float16* __restrict__ e1,
    float* __restrict__ colsum, float* __restrict__ colsumsq) {
  const int mlp = blockIdx.z;
  const _Float16* X = h1 + (size_t)mlp * (NROWS * FDIM);
  const _Float16* wp = w2p + mlp * 65536;
  _Float16* out = e1 + (size_t)mlp * (NROWS * FDIM);
  const float* bias = p.b2[mlp];
  int lane = threadIdx.x & 63, wave = threadIdx.x >> 6;
  int lm = lane & 15, lq = lane >> 4;
  int m0 = blockIdx.x * 64 + wave * 16;
  int n0 = blockIdx.y * 64;
  floatx4 acc[4];
  #pragma unroll
  for (int t = 0; t < 4; ++t) acc[t] = (floatx4){0.f, 0.f, 0.f, 0.f};
  const half8_t* ap = (const half8_t*)(X + (size_t)(m0 + lm) * 256 + lq * 8);
  const half8_t* wp8 = (const half8_t*)wp;
  #pragma unroll
  for (int kt = 0; kt < 8; ++kt) {
    half8_t a = ap[kt * 4];
    #pragma unroll
    for (int t = 0; t < 4; ++t) {
      half8_t b = wp8[(((n0 >> 4) + t) * 8 + kt) * 64 + lane];
      acc[t] = __builtin_amdgcn_mfma_f32_16x16x32_f16(a, b, acc[t], 0, 0, 0);
    }
  }
  #pragma unroll
  for (int t = 0; t < 4; ++t) {
    int col = n0 + t * 16 + lm;
    float bb = bias[col];
    float s = 0.f, s2 = 0.f;
    #pragma unroll
    for (int r = 0; r < 4; ++r) {
      float v = acc[t][r] + bb;
      v = (v >= 0.f) ? v : 0.01f * v;
      out[(size_t)(m0 + lq * 4 + r) * FDIM + col] = (_Float16)v;
      s += v; s2 += v * v;
    }
    s  += __shfl_xor(s, 16, 64);  s  += __shfl_xor(s, 32, 64);
    s2 += __shfl_xor(s2, 16, 64); s2 += __shfl_xor(s2, 32, 64);
    if (lq == 0) {
      atomicAdd(&colsum[mlp * FDIM + col], s);
      atomicAdd(&colsumsq[mlp * FDIM + col], s2);
    }
  }
}

// ---------------------------------------------------------------------------
// BN normalize in-place (fp16); mlp==2 also accumulates S_all (post-round).
// ---------------------------------------------------------------------------
__global__ __launch_bounds__(256) void norm_kernel(
    _Float16* __restrict__ e1, const float* __restrict__ colsum,
    const float* __restrict__ colsumsq, MlpPtrs p, float* __restrict__ S_all) {
  int mlp = blockIdx.y;
  int c = threadIdx.x;
  _Float16* h = e1 + (size_t)mlp * (NROWS * FDIM);
  float mean = colsum[mlp * FDIM + c] * (1.f / NROWS);
  float var = colsumsq[mlp * FDIM + c] * (1.f / NROWS) - mean * mean;
  float scale = p.gamma[mlp][c] * rsqrtf(var + 1e-5f);
  float shift = p.beta[mlp][c] - mean * scale;
  int r0 = blockIdx.x * 32;
  float sv = 0.f;
  for (int r = 0; r < 32; ++r) {
    size_t idx = (size_t)(r0 + r) * FDIM + c;
    float v = (float)h[idx] * scale + shift;
    _Float16 hv = (_Float16)v;
    h[idx] = hv;
    sv += (float)hv;
  }
  if (mlp == 2) atomicAdd(&S_all[c], sv);
}

// ---------------------------------------------------------------------------
// Fused: A-row scan (nontemporal stream) + sparse SDDMM + softmax-with-
// implicit-zeros + SpMM.  One block per row, 4 waves, 3 barriers.
//   scan:   compact nonzero cols of A[i,:] into LDS
//   SDDMM:  16-lane group per edge (4/wave), 32 B/lane coalesced, 4 shfl hops
//   softmax: computed redundantly per wave from LDS scores (no barrier)
//   SpMM:   2 edges/wave (half8 = 16 B/lane), parity combine via shfl_xor(32)
// ---------------------------------------------------------------------------
__global__ __launch_bounds__(256) void attn_kernel(
    const float* __restrict__ A,
    const _Float16* __restrict__ e1, const float* __restrict__ S_all,
    float* __restrict__ out) {
  const _Float16* qe = e1;
  const _Float16* ke = e1 + (size_t)1 * NROWS * FDIM;
  const _Float16* ve = e1 + (size_t)2 * NROWS * FDIM;
  int i = blockIdx.x;
  int tid = threadIdx.x, lane = tid & 63, wave = tid >> 6;
  __shared__ int sj[CAP];
  __shared__ float sw[CAP];   // raw scaled scores
  __shared__ float pacc[4][FDIM];
  __shared__ int s_cnt;
  if (tid == 0) s_cnt = 0;
  __syncthreads();

  // -------- scan A row i (nontemporal stream; preload all 8 vectors)
  const floatx4* row = (const floatx4*)(A + (size_t)i * NROWS);
  floatx4 av[8];
  #pragma unroll
  for (int it = 0; it < 8; ++it)
    av[it] = __builtin_nontemporal_load(&row[it * 256 + tid]);
  #pragma unroll
  for (int it = 0; it < 8; ++it) {
    int v4 = it * 256 + tid;
    int cols[4]; int c = 0;
    if (av[it][0] != 0.f) cols[c++] = v4 * 4 + 0;
    if (av[it][1] != 0.f) cols[c++] = v4 * 4 + 1;
    if (av[it][2] != 0.f) cols[c++] = v4 * 4 + 2;
    if (av[it][3] != 0.f) cols[c++] = v4 * 4 + 3;
    if (c) {
      int pos = atomicAdd(&s_cnt, c);
      for (int l = 0; l < c; ++l) if (pos + l < CAP) sj[pos + l] = cols[l];
    }
  }
  __syncthreads();
  int nnz = s_cnt < CAP ? s_cnt : CAP;

  // -------- SDDMM: 16-lane group per edge, 4 edges per wave per iteration
  int cl = lane & 15, g = lane >> 4;
  const half8_t* qe8 = (const half8_t*)(qe + (size_t)i * FDIM + cl * 16);
  half8_t qa = qe8[0], qb = qe8[1];
  for (int e = wave * 4 + g; e < nnz; e += 16) {
    int j = sj[e];
    const half8_t* ke8 = (const half8_t*)(ke + (size_t)j * FDIM + cl * 16);
    half8_t ka = ke8[0], kb = ke8[1];
    float s = 0.f;
    #pragma unroll
    for (int r = 0; r < 8; ++r)
      s += (float)qa[r] * (float)ka[r] + (float)qb[r] * (float)kb[r];
    #pragma unroll
    for (int off = 8; off >= 1; off >>= 1) s += __shfl_xor(s, off, 64);
    if (cl == 0) sw[e] = s * 0.0625f;
  }
  __syncthreads();

  // -------- softmax reduction, redundant per wave (no extra barrier)
  float v0 = lane < nnz ? sw[lane] : 0.f;
  float v1 = lane + 64 < nnz ? sw[lane + 64] : 0.f;
  float m = fmaxf(fmaxf(v0, v1), 0.f);  // background zeros participate
  #pragma unroll
  for (int off = 32; off >= 1; off >>= 1) m = fmaxf(m, __shfl_xor(m, off, 64));
  float em = __expf(-m);
  float w0 = lane < nnz ? __expf(v0 - m) : 0.f;
  float w1 = lane + 64 < nnz ? __expf(v1 - m) : 0.f;
  float ls = w0 + w1;
  #pragma unroll
  for (int off = 32; off >= 1; off >>= 1) ls += __shfl_xor(ls, off, 64);
  float inv = 1.f / (ls + (float)(NROWS - nnz) * em);

  // -------- SpMM: 2 edges per wave per iteration, lane covers 8 cols
  int par = lane >> 5, c8 = lane & 31;
  floatx4 accA = (floatx4){0.f, 0.f, 0.f, 0.f};
  floatx4 accB = (floatx4){0.f, 0.f, 0.f, 0.f};
  for (int e = wave * 2 + par; e < nnz; e += 8) {
    int j = sj[e];
    float w = __expf(sw[e] - m) - em;  // edge weight minus background
    half8_t vv = *(const half8_t*)(ve + (size_t)j * FDIM + c8 * 8);
    accA[0] += w * (float)vv[0]; accA[1] += w * (float)vv[1];
    accA[2] += w * (float)vv[2]; accA[3] += w * (float)vv[3];
    accB[0] += w * (float)vv[4]; accB[1] += w * (float)vv[5];
    accB[2] += w * (float)vv[6]; accB[3] += w * (float)vv[7];
  }
  #pragma unroll
  for (int r = 0; r < 4; ++r) {
    accA[r] += __shfl_xor(accA[r], 32, 64);
    accB[r] += __shfl_xor(accB[r], 32, 64);
  }
  if (par == 0) {
    ((floatx4*)&pacc[wave][c8 * 8])[0] = accA;
    ((floatx4*)&pacc[wave][c8 * 8])[1] = accB;
  }
  __syncthreads();

  int c = tid;
  float s = pacc[0][c] + pacc[1][c] + pacc[2][c] + pacc[3][c] + em * S_all[c];
  __builtin_nontemporal_store(s * inv, &out[(size_t)i * FDIM + c]);
}

// ---------------------------------------------------------------------------
extern "C" void kernel_launch(void* const* d_in, const int* in_sizes, int n_in,
                              void* d_out, int out_size, void* d_ws, size_t ws_size,
                              hipStream_t stream) {
  const float* A = (const float*)d_in[0];
  const float* q = (const float*)d_in[1];
  const float* k = (const float*)d_in[2];
  MlpPtrs p;
  for (int m = 0; m < 3; ++m) {
    const int b = 3 + m * 6;
    p.w1[m]    = (const float*)d_in[b + 0];
    p.b1[m]    = (const float*)d_in[b + 1];
    p.w2[m]    = (const float*)d_in[b + 2];
    p.b2[m]    = (const float*)d_in[b + 3];
    p.gamma[m] = (const float*)d_in[b + 4];
    p.beta[m]  = (const float*)d_in[b + 5];
  }
  char* ws = (char*)d_ws;
  const size_t MB = 1024 * 1024;
  _Float16* qh  = (_Float16*)(ws + 0);                 // 2 MB
  _Float16* kh  = (_Float16*)(ws + 2 * MB);            // 2 MB
  _Float16* h1  = (_Float16*)(ws + 4 * MB);            // 12 MB (3 x 4MB)
  _Float16* e1  = (_Float16*)(ws + 16 * MB);           // 12 MB (3 x 4MB)
  _Float16* w1p = (_Float16*)(ws + 28 * MB);           // 192 KB
  _Float16* w2p = (_Float16*)(ws + 28 * MB + 192 * 1024); // 384 KB
  float* colsum   = (float*)(ws + 28 * MB + 640 * 1024);  // 3*256 f
  float* colsumsq = colsum + 3 * FDIM;                    // 3*256 f
  float* S_all    = colsumsq + 3 * FDIM;                  // 256 f

  (void)hipMemsetAsync(colsum, 0, 7 * 1024, stream);
  prep_kernel<<<dim3(256, 8, 1), 256, 0, stream>>>(q, k, p, qh, kh, w1p, w2p);
  gemm1_kernel<<<dim3(128, 4, 3), 256, 0, stream>>>(qh, kh, w1p, p, h1);
  gemm2_kernel<<<dim3(128, 4, 3), 256, 0, stream>>>(h1, w2p, p, e1, colsum, colsumsq);
  norm_kernel<<<dim3(256, 3, 1), 256, 0, stream>>>(e1, colsum, colsumsq, p, S_all);
  attn_kernel<<<NROWS, 256, 0, stream>>>(A, e1, S_all, (float*)d_out);
}

// Round 5
// 455.250 us; speedup vs baseline: 1.1690x; 1.0060x over previous
//
#include <hip/hip_runtime.h>

#define NROWS 8192
#define FDIM 256
#define CAP 128   // max edges per row (Binomial n=8192 p=.004: mean 33, max ~60)

typedef _Float16 half8_t __attribute__((ext_vector_type(8)));
typedef _Float16 half4_t __attribute__((ext_vector_type(4)));
typedef float floatx4 __attribute__((ext_vector_type(4)));

struct MlpPtrs {
  const float* w1[3]; const float* b1[3];
  const float* w2[3]; const float* b2[3];
  const float* gamma[3]; const float* beta[3];
};

// ---------------------------------------------------------------------------
// Weight pack only. Tasks 0..2: w1[m]; 3..5: w2[m].
// Packed layout: ((n_tile*ktiles + k_tile)*64 + lane)*8 + j holds
// W[k_tile*32 + (lane>>4)*8 + j][n_tile*16 + (lane&15)].
// ---------------------------------------------------------------------------
__global__ __launch_bounds__(256) void prep_kernel(
    MlpPtrs p, _Float16* __restrict__ w1p, _Float16* __restrict__ w2p) {
  int task = blockIdx.y;
  int tid = blockIdx.x * 256 + threadIdx.x;
  int m = task % 3;
  bool isw2 = task >= 3;
  int K = isw2 ? 256 : 128;
  if (tid >= K * 256) return;
  const float* src = isw2 ? p.w2[m] : p.w1[m];
  _Float16* dst = isw2 ? (w2p + m * 65536) : (w1p + m * 32768);
  int j = tid & 7, lane = (tid >> 3) & 63, rest = tid >> 9;
  int ktiles = K >> 5;
  int k_tile = rest % ktiles, n_tile = rest / ktiles;
  int kk = k_tile * 32 + (lane >> 4) * 8 + j;
  int nn = n_tile * 16 + (lane & 15);
  dst[tid] = (_Float16)src[kk * 256 + nn];
}

// ---------------------------------------------------------------------------
// GEMM1: h1 = leaky(X @ w1 + b1).  X: [8192,128] fp32 (converted inline).
// ---------------------------------------------------------------------------
__global__ __launch_bounds__(256) void gemm1_kernel(
    const float* __restrict__ q, const float* __restrict__ k,
    const _Float16* __restrict__ w1p, MlpPtrs p, _Float16* __restrict__ h1) {
  const int mlp = blockIdx.z;
  const float* X = (mlp == 0) ? q : k;   // mlp 1 (k) and 2 (v) both read input k
  const _Float16* wp = w1p + mlp * 32768;
  _Float16* out = h1 + (size_t)mlp * (NROWS * FDIM);
  const float* bias = p.b1[mlp];
  int lane = threadIdx.x & 63, wave = threadIdx.x >> 6;
  int lm = lane & 15, lq = lane >> 4;
  int m0 = blockIdx.x * 64 + wave * 16;
  int n0 = blockIdx.y * 64;
  floatx4 acc[4];
  #pragma unroll
  for (int t = 0; t < 4; ++t) acc[t] = (floatx4){0.f, 0.f, 0.f, 0.f};
  const float* ap = X + (size_t)(m0 + lm) * 128 + lq * 8;
  const half8_t* wp8 = (const half8_t*)wp;
  #pragma unroll
  for (int kt = 0; kt < 4; ++kt) {
    floatx4 a0 = *(const floatx4*)(ap + kt * 32);
    floatx4 a1 = *(const floatx4*)(ap + kt * 32 + 4);
    half8_t a = (half8_t){(_Float16)a0[0], (_Float16)a0[1], (_Float16)a0[2], (_Float16)a0[3],
                          (_Float16)a1[0], (_Float16)a1[1], (_Float16)a1[2], (_Float16)a1[3]};
    #pragma unroll
    for (int t = 0; t < 4; ++t) {
      half8_t b = wp8[(((n0 >> 4) + t) * 4 + kt) * 64 + lane];
      acc[t] = __builtin_amdgcn_mfma_f32_16x16x32_f16(a, b, acc[t], 0, 0, 0);
    }
  }
  #pragma unroll
  for (int t = 0; t < 4; ++t) {
    int col = n0 + t * 16 + lm;
    float bb = bias[col];
    #pragma unroll
    for (int r = 0; r < 4; ++r) {
      float v = acc[t][r] + bb;
      v = (v >= 0.f) ? v : 0.01f * v;
      out[(size_t)(m0 + lq * 4 + r) * FDIM + col] = (_Float16)v;
    }
  }
}

// ---------------------------------------------------------------------------
// GEMM2: e1_raw = leaky(h1 @ w2 + b2) (pre-BN) + column sum/sumsq atomics.
// ---------------------------------------------------------------------------
__global__ __launch_bounds__(256) void gemm2_kernel(
    const _Float16* __restrict__ h1, const _Float16* __restrict__ w2p,
    MlpPtrs p, _Float16* __restrict__ e1,
    float* __restrict__ colsum, float* __restrict__ colsumsq) {
  const int mlp = blockIdx.z;
  const _Float16* X = h1 + (size_t)mlp * (NROWS * FDIM);
  const _Float16* wp = w2p + mlp * 65536;
  _Float16* out = e1 + (size_t)mlp * (NROWS * FDIM);
  const float* bias = p.b2[mlp];
  int lane = threadIdx.x & 63, wave = threadIdx.x >> 6;
  int lm = lane & 15, lq = lane >> 4;
  int m0 = blockIdx.x * 64 + wave * 16;
  int n0 = blockIdx.y * 64;
  floatx4 acc[4];
  #pragma unroll
  for (int t = 0; t < 4; ++t) acc[t] = (floatx4){0.f, 0.f, 0.f, 0.f};
  const half8_t* ap = (const half8_t*)(X + (size_t)(m0 + lm) * 256 + lq * 8);
  const half8_t* wp8 = (const half8_t*)wp;
  #pragma unroll
  for (int kt = 0; kt < 8; ++kt) {
    half8_t a = ap[kt * 4];
    #pragma unroll
    for (int t = 0; t < 4; ++t) {
      half8_t b = wp8[(((n0 >> 4) + t) * 8 + kt) * 64 + lane];
      acc[t] = __builtin_amdgcn_mfma_f32_16x16x32_f16(a, b, acc[t], 0, 0, 0);
    }
  }
  #pragma unroll
  for (int t = 0; t < 4; ++t) {
    int col = n0 + t * 16 + lm;
    float bb = bias[col];
    float s = 0.f, s2 = 0.f;
    #pragma unroll
    for (int r = 0; r < 4; ++r) {
      float v = acc[t][r] + bb;
      v = (v >= 0.f) ? v : 0.01f * v;
      out[(size_t)(m0 + lq * 4 + r) * FDIM + col] = (_Float16)v;
      s += v; s2 += v * v;
    }
    s  += __shfl_xor(s, 16, 64);  s  += __shfl_xor(s, 32, 64);
    s2 += __shfl_xor(s2, 16, 64); s2 += __shfl_xor(s2, 32, 64);
    if (lq == 0) {
      atomicAdd(&colsum[mlp * FDIM + col], s);
      atomicAdd(&colsumsq[mlp * FDIM + col], s2);
    }
  }
}

// ---------------------------------------------------------------------------
// BN stats -> affine scale/shift per (mlp, col). One block.
// ---------------------------------------------------------------------------
__global__ __launch_bounds__(256) void stats_kernel(
    const float* __restrict__ colsum, const float* __restrict__ colsumsq,
    MlpPtrs p, float* __restrict__ scaleA, float* __restrict__ shiftA) {
  int c = threadIdx.x;
  #pragma unroll
  for (int m = 0; m < 3; ++m) {
    float mean = colsum[m * FDIM + c] * (1.f / NROWS);
    float var = colsumsq[m * FDIM + c] * (1.f / NROWS) - mean * mean;
    float sc = p.gamma[m][c] * rsqrtf(var + 1e-5f);
    scaleA[m * FDIM + c] = sc;
    shiftA[m * FDIM + c] = p.beta[m][c] - mean * sc;
  }
}

// ---------------------------------------------------------------------------
// Fused attention, wave-per-row, barrier-free (all LDS is wave-private).
//   scan:   64 lanes stream 32 KB row (nontemporal), compact cols into sj
//   SDDMM:  16-lane group per edge; BN affine folded into qk[]/qb per row
//   softmax: wave shuffle reduce; weights (w-em) cached in sw
//   SpMM:   1 edge/iter, 64 lanes x half4 = 256 cols; BN-v affine applied
//           algebraically in the epilogue.
// ---------------------------------------------------------------------------
__global__ __launch_bounds__(256) void attn_kernel(
    const float* __restrict__ A, const _Float16* __restrict__ e1,
    const float* __restrict__ scaleA, const float* __restrict__ shiftA,
    const float* __restrict__ colsum, float* __restrict__ out) {
  const _Float16* qe = e1;
  const _Float16* ke = e1 + (size_t)1 * NROWS * FDIM;
  const _Float16* ve = e1 + (size_t)2 * NROWS * FDIM;
  int lane = threadIdx.x & 63, wave = threadIdx.x >> 6;
  int i = blockIdx.x * 4 + wave;
  __shared__ int sj[4][CAP];
  __shared__ float sw[4][CAP];
  __shared__ int cnt[4];
  if (lane == 0) cnt[wave] = 0;

  // -------- scan A row i (nontemporal stream, 32 float4/lane in 4 batches)
  const floatx4* row = (const floatx4*)(A + (size_t)i * NROWS);
  for (int b = 0; b < 4; ++b) {
    floatx4 av[8];
    #pragma unroll
    for (int it = 0; it < 8; ++it)
      av[it] = __builtin_nontemporal_load(&row[(b * 8 + it) * 64 + lane]);
    #pragma unroll
    for (int it = 0; it < 8; ++it) {
      int base = ((b * 8 + it) * 64 + lane) * 4;
      int cols[4]; int c = 0;
      if (av[it][0] != 0.f) cols[c++] = base + 0;
      if (av[it][1] != 0.f) cols[c++] = base + 1;
      if (av[it][2] != 0.f) cols[c++] = base + 2;
      if (av[it][3] != 0.f) cols[c++] = base + 3;
      if (c) {
        int pos = atomicAdd(&cnt[wave], c);
        for (int l = 0; l < c; ++l) if (pos + l < CAP) sj[wave][pos + l] = cols[l];
      }
    }
  }
  int nnz = cnt[wave] < CAP ? cnt[wave] : CAP;

  // -------- per-row q setup: qk[c] = (sq*q+hq)*sk/16, qb = sum (sq*q+hq)*hk/16
  int cl = lane & 15, g = lane >> 4;
  const half8_t* qp = (const half8_t*)(qe + (size_t)i * FDIM + cl * 16);
  half8_t qa = qp[0], qb8 = qp[1];
  const floatx4* sq4 = (const floatx4*)(scaleA + cl * 16);
  const floatx4* hq4 = (const floatx4*)(shiftA + cl * 16);
  const floatx4* sk4 = (const floatx4*)(scaleA + FDIM + cl * 16);
  const floatx4* hk4 = (const floatx4*)(shiftA + FDIM + cl * 16);
  float qk[16]; float qb = 0.f;
  #pragma unroll
  for (int v4 = 0; v4 < 4; ++v4) {
    floatx4 sq = sq4[v4], hq = hq4[v4], sk = sk4[v4], hk = hk4[v4];
    #pragma unroll
    for (int r = 0; r < 4; ++r) {
      int c = v4 * 4 + r;
      float qr = (c < 8) ? (float)qa[c] : (float)qb8[c - 8];
      float qn = qr * sq[r] + hq[r];
      qk[c] = qn * sk[r] * 0.0625f;
      qb += qn * hk[r] * 0.0625f;
    }
  }

  // -------- SDDMM: 4 edges in parallel (16-lane groups)
  for (int e = g; e < nnz; e += 4) {
    int j = sj[wave][e];
    const half8_t* kp = (const half8_t*)(ke + (size_t)j * FDIM + cl * 16);
    half8_t ka = kp[0], kb = kp[1];
    float s = qb;
    #pragma unroll
    for (int r = 0; r < 8; ++r)
      s += qk[r] * (float)ka[r] + qk[r + 8] * (float)kb[r];
    #pragma unroll
    for (int off = 8; off >= 1; off >>= 1) s += __shfl_xor(s, off, 64);
    if (cl == 0) sw[wave][e] = s;
  }

  // -------- softmax over {scores} U {8192-nnz implicit zeros}
  float v0 = lane < nnz ? sw[wave][lane] : 0.f;
  float v1 = lane + 64 < nnz ? sw[wave][lane + 64] : 0.f;
  float m = fmaxf(fmaxf(v0, v1), 0.f);
  #pragma unroll
  for (int off = 32; off >= 1; off >>= 1) m = fmaxf(m, __shfl_xor(m, off, 64));
  float em = __expf(-m);
  float w0 = lane < nnz ? __expf(v0 - m) : 0.f;
  float w1 = lane + 64 < nnz ? __expf(v1 - m) : 0.f;
  float ls = w0 + w1;
  #pragma unroll
  for (int off = 32; off >= 1; off >>= 1) ls += __shfl_xor(ls, off, 64);
  if (lane < nnz) sw[wave][lane] = w0 - em;
  if (lane + 64 < nnz) sw[wave][lane + 64] = w1 - em;
  float wsum = ls - (float)nnz * em;                      // sum of (w_e - em)
  float inv = 1.f / (ls + (float)(NROWS - nnz) * em);     // softmax denom

  // -------- SpMM on raw ve: 64 lanes x 4 cols = 256
  floatx4 acc = (floatx4){0.f, 0.f, 0.f, 0.f};
  for (int e = 0; e < nnz; ++e) {
    int j = sj[wave][e];
    float w = sw[wave][e];
    half4_t vv = *(const half4_t*)(ve + (size_t)j * FDIM + lane * 4);
    acc[0] += w * (float)vv[0]; acc[1] += w * (float)vv[1];
    acc[2] += w * (float)vv[2]; acc[3] += w * (float)vv[3];
  }

  // -------- epilogue: fold BN-v affine + uniform background
  floatx4 sv = *(const floatx4*)(scaleA + 2 * FDIM + lane * 4);
  floatx4 sh = *(const floatx4*)(shiftA + 2 * FDIM + lane * 4);
  floatx4 cs = *(const floatx4*)(colsum + 2 * FDIM + lane * 4);
  float bg = wsum + em * (float)NROWS;
  floatx4 o;
  #pragma unroll
  for (int r = 0; r < 4; ++r)
    o[r] = inv * (sv[r] * (acc[r] + em * cs[r]) + sh[r] * bg);
  __builtin_nontemporal_store(o, (floatx4*)(out + (size_t)i * FDIM + lane * 4));
}

// ---------------------------------------------------------------------------
extern "C" void kernel_launch(void* const* d_in, const int* in_sizes, int n_in,
                              void* d_out, int out_size, void* d_ws, size_t ws_size,
                              hipStream_t stream) {
  const float* A = (const float*)d_in[0];
  const float* q = (const float*)d_in[1];
  const float* k = (const float*)d_in[2];
  MlpPtrs p;
  for (int m = 0; m < 3; ++m) {
    const int b = 3 + m * 6;
    p.w1[m]    = (const float*)d_in[b + 0];
    p.b1[m]    = (const float*)d_in[b + 1];
    p.w2[m]    = (const float*)d_in[b + 2];
    p.b2[m]    = (const float*)d_in[b + 3];
    p.gamma[m] = (const float*)d_in[b + 4];
    p.beta[m]  = (const float*)d_in[b + 5];
  }
  char* ws = (char*)d_ws;
  const size_t MB = 1024 * 1024;
  _Float16* h1  = (_Float16*)(ws + 0);                 // 12 MB (3 x 4MB)
  _Float16* e1  = (_Float16*)(ws + 12 * MB);           // 12 MB (3 x 4MB), raw pre-BN
  _Float16* w1p = (_Float16*)(ws + 24 * MB);           // 192 KB
  _Float16* w2p = (_Float16*)(ws + 24 * MB + 192 * 1024); // 384 KB
  float* colsum   = (float*)(ws + 25 * MB);            // 3*256 f
  float* colsumsq = colsum + 3 * FDIM;                 // 3*256 f
  float* scaleA   = colsumsq + 3 * FDIM;               // 3*256 f
  float* shiftA   = scaleA + 3 * FDIM;                 // 3*256 f

  (void)hipMemsetAsync(colsum, 0, 2 * 3 * FDIM * sizeof(float), stream);
  prep_kernel<<<dim3(256, 6, 1), 256, 0, stream>>>(p, w1p, w2p);
  gemm1_kernel<<<dim3(128, 4, 3), 256, 0, stream>>>(q, k, w1p, p, h1);
  gemm2_kernel<<<dim3(128, 4, 3), 256, 0, stream>>>(h1, w2p, p, e1, colsum, colsumsq);
  stats_kernel<<<1, 256, 0, stream>>>(colsum, colsumsq, p, scaleA, shiftA);
  attn_kernel<<<NROWS / 4, 256, 0, stream>>>(A, e1, scaleA, shiftA, colsum, (float*)d_out);
}